// Round 15
// baseline (419.616 us; speedup 1.0000x reference)
//
#include <hip/hip_runtime.h>
#include <stdint.h>

// MHA forward, MI355X.
//   0) cvt: q/k/v fp32 -> bf16   1) wtrans: W -> Wt bf16
//   2) proj GEMMs (bf16, global_load_lds staging)
//   3a) pass1_kernel (R15 split): l[bh][s] = sum_k 2^t, 16KB LDS -> 8 blocks/CU
//       (was embedded in the 40KB-LDS attn kernel at 4 blocks/CU -> latency-bound,
//       R10: Occupancy 30%). Depth-2 prefetch (R13). l -> ws[0..512KB], which
//       aliases transposed-Wq (dead after the q-projection GEMM).
//   3b) attn pass2: reads l, p=2^(t-log2 l) via MFMA C-init, full-line
//       LDS-remapped NT stores (R14: -75us), PV via MFMA.
//   4) out-proj GEMM -> fp32
//
// MFMA 16x16x32 bf16, k-chunk c = ks*4+g. C/D: col=lane&15, row=(lane>>4)*4+reg.

using bf16x8 = __attribute__((ext_vector_type(8))) short;
using f32x4  = __attribute__((ext_vector_type(4))) float;
using u16x4  = __attribute__((ext_vector_type(4))) unsigned short;
using u64x2  = __attribute__((ext_vector_type(2))) unsigned long long;

#define MFMA_BF16 __builtin_amdgcn_mfma_f32_16x16x32_bf16

__device__ __forceinline__ unsigned short f2bf(float x) {
    unsigned int u = __builtin_bit_cast(unsigned int, x);
    u = (u + 0x7FFFu + ((u >> 16) & 1u)) >> 16;   // RNE
    return (unsigned short)u;
}
__device__ __forceinline__ float bf2f(unsigned short u) {
    return __builtin_bit_cast(float, (unsigned int)u << 16);
}
__device__ __forceinline__ float exp2_fast(float x) {
    float r; asm("v_exp_f32 %0, %1" : "=v"(r) : "v"(x)); return r;
}
__device__ __forceinline__ float log2_fast(float x) {
    float r; asm("v_log_f32 %0, %1" : "=v"(r) : "v"(x)); return r;
}
__device__ __forceinline__ void gload_lds16(const unsigned short* g, bf16x8* l) {
    __builtin_amdgcn_global_load_lds(
        (const __attribute__((address_space(1))) unsigned int*)(g),
        (__attribute__((address_space(3))) unsigned int*)(l), 16, 0, 0);
}

// ---------------- fp32 -> bf16 convert (q,k,v) ----------------
__global__ __launch_bounds__(256) void cvt_kernel(
    const float* __restrict__ q, const float* __restrict__ k,
    const float* __restrict__ v, unsigned short* __restrict__ dst)
{
    const float* src = (blockIdx.y == 0) ? q : (blockIdx.y == 1) ? k : v;
    unsigned short* d = dst + (size_t)blockIdx.y * 8388608;
    size_t i = ((size_t)blockIdx.x * 256 + threadIdx.x) * 8;
    float4 a = *(const float4*)(src + i);
    float4 b = *(const float4*)(src + i + 4);
    u16x4 lo = {f2bf(a.x), f2bf(a.y), f2bf(a.z), f2bf(a.w)};
    u16x4 hi = {f2bf(b.x), f2bf(b.y), f2bf(b.z), f2bf(b.w)};
    *(u16x4*)(d + i) = lo;
    *(u16x4*)(d + i + 4) = hi;
}

// ---------------- weight transpose + bf16 convert ----------------
__global__ __launch_bounds__(256) void wtrans_kernel(
    const float* __restrict__ w0, const float* __restrict__ w1,
    const float* __restrict__ w2, const float* __restrict__ w3,
    unsigned short* __restrict__ Wt)
{
    __shared__ float tile[64][65];
    const float* src = (blockIdx.z == 0) ? w0 : (blockIdx.z == 1) ? w1 :
                       (blockIdx.z == 2) ? w2 : w3;
    unsigned short* dst = Wt + (size_t)blockIdx.z * (1u << 20);
    const int k0 = blockIdx.x * 64, n0 = blockIdx.y * 64;
    const int tid = threadIdx.x;
#pragma unroll
    for (int i = 0; i < 16; ++i) {
        int idx = i * 256 + tid;
        int kk = idx >> 6, nn = idx & 63;
        tile[kk][nn] = src[(size_t)(k0 + kk) * 1024 + n0 + nn];
    }
    __syncthreads();
#pragma unroll
    for (int i = 0; i < 16; ++i) {
        int idx = i * 256 + tid;
        int nn = idx >> 6, kk = idx & 63;
        dst[(size_t)(n0 + nn) * 1024 + k0 + kk] = f2bf(tile[kk][nn]);
    }
}

// ---------------- GEMM: C[8192,1024] = A[8192,1024](bf16) @ Bt^T + bias ----------
// OUT_MODE 0: bf16 [b][h][s][d]; 1: bf16 [b][h][d][s]; 2: fp32 row-major
template<int OUT_MODE>
__global__ __launch_bounds__(256) void gemm_kernel(
    const unsigned short* __restrict__ A, const unsigned short* __restrict__ Bt,
    const float* __restrict__ bias, void* __restrict__ Cp, float prescale)
{
    __shared__ bf16x8 Alds[1024];    // 128 rows x 8 chunks, slot-linear
    __shared__ bf16x8 Blds[1024];
    const int tid = threadIdx.x;
    const int lane = tid & 63;
    const int w = tid >> 6;
    const int wm = w >> 1, wn = w & 1;
    const int m0 = blockIdx.x * 128, n0 = blockIdx.y * 128;
    const int r16 = lane & 15, g = lane >> 4;

    f32x4 acc[4][4] = {};

    for (int kt = 0; kt < 16; ++kt) {
        const int k0 = kt * 64;
#pragma unroll
        for (int issue = 0; issue < 4; ++issue) {
            int s = issue * 256 + tid;
            int row = s >> 3, cc = (s & 7) ^ (row & 7);   // pre-swizzled source chunk
            gload_lds16(A  + (size_t)(m0 + row) * 1024 + k0 + cc * 8,
                        &Alds[issue * 256 + w * 64]);
            gload_lds16(Bt + (size_t)(n0 + row) * 1024 + k0 + cc * 8,
                        &Blds[issue * 256 + w * 64]);
        }
        __syncthreads();
#pragma unroll
        for (int ks = 0; ks < 2; ++ks) {
            bf16x8 af[4], bfr[4];
#pragma unroll
            for (int mf = 0; mf < 4; ++mf) {
                int row = wm * 64 + mf * 16 + r16;
                af[mf] = Alds[row * 8 + ((ks * 4 + g) ^ (row & 7))];
            }
#pragma unroll
            for (int nf = 0; nf < 4; ++nf) {
                int row = wn * 64 + nf * 16 + r16;
                bfr[nf] = Blds[row * 8 + ((ks * 4 + g) ^ (row & 7))];
            }
#pragma unroll
            for (int mf = 0; mf < 4; ++mf)
#pragma unroll
                for (int nf = 0; nf < 4; ++nf)
                    acc[mf][nf] = MFMA_BF16(af[mf], bfr[nf], acc[mf][nf], 0, 0, 0);
        }
        __syncthreads();
    }

#pragma unroll
    for (int nf = 0; nf < 4; ++nf) {
        const int n = n0 + wn * 64 + nf * 16 + r16;
        const float bv = bias[n];
#pragma unroll
        for (int mf = 0; mf < 4; ++mf) {
            const int mb = m0 + wm * 64 + mf * 16 + g * 4;
            if constexpr (OUT_MODE == 2) {
                float* C = (float*)Cp;
#pragma unroll
                for (int r = 0; r < 4; ++r)
                    C[(size_t)(mb + r) * 1024 + n] = acc[mf][nf][r] + bv;
            } else if constexpr (OUT_MODE == 0) {
                unsigned short* C = (unsigned short*)Cp;
                const int h = n >> 6, d = n & 63;
#pragma unroll
                for (int r = 0; r < 4; ++r) {
                    int m = mb + r;
                    int b = m >> 11, s2 = m & 2047;
                    C[((((size_t)b * 16 + h) * 2048 + s2) << 6) + d] =
                        f2bf((acc[mf][nf][r] + bv) * prescale);
                }
            } else {
                unsigned short* C = (unsigned short*)Cp;
                const int h = n >> 6, d = n & 63;
                const int b = mb >> 11, s2 = mb & 2047;
                u16x4 pk;
#pragma unroll
                for (int r = 0; r < 4; ++r) pk[r] = f2bf(acc[mf][nf][r] + bv);
                *(u16x4*)(C + (((size_t)b * 16 + h) * 64 + d) * 2048 + s2) = pk;
            }
        }
    }
}

// ---------------- pass 1: l[bh][s] = sum_k 2^t  (standalone, 16KB LDS) --------
// Same XCD map / wave logic / depth-2 prefetch as before; 8 blocks/CU now.
__global__ __launch_bounds__(256) void pass1_kernel(
    const unsigned short* __restrict__ Q,    // [bh][2048][64] bf16 (pre-scaled)
    const unsigned short* __restrict__ K,    // [bh][2048][64] bf16
    float* __restrict__ lbuf)                // [bh][2048] f32
{
    __shared__ bf16x8 k_buf[2][64 * 8];      // 16 KB dbuf

    const int tid = threadIdx.x;
    const int lane = tid & 63;
    const int w = tid >> 6;
    const int L = blockIdx.x;
    const int xcd = L & 7, j = L >> 3;
    const int qt = j & 31;
    const int bh = ((j >> 5) << 3) | xcd;
    const int r16 = lane & 15, g = lane >> 4;

    const unsigned short* Kb = K + (size_t)bh * 2048 * 64;

    const int row0 = tid >> 3, cc0 = tid & 7;
    const int row1 = row0 + 32;
    const int kslot0 = row0 * 8 + (cc0 ^ (row0 & 7));
    const int kslot1 = row1 * 8 + (cc0 ^ (row1 & 7));

    const int qrow = w * 16 + r16;
    const unsigned short* qptr = Q + ((size_t)bh * 2048 + (size_t)qt * 64 + qrow) * 64 + g * 8;
    const bf16x8 qf0 = *(const bf16x8*)(qptr);
    const bf16x8 qf1 = *(const bf16x8*)(qptr + 32);

    k_buf[0][kslot0] = *(const bf16x8*)(Kb + (size_t)row0 * 64 + cc0 * 8);
    k_buf[0][kslot1] = *(const bf16x8*)(Kb + (size_t)row1 * 64 + cc0 * 8);
    bf16x8 pf0 = *(const bf16x8*)(Kb + 4096 + (size_t)row0 * 64 + cc0 * 8);
    bf16x8 pf1 = *(const bf16x8*)(Kb + 4096 + (size_t)row1 * 64 + cc0 * 8);
    __syncthreads();

    float l4[4] = {0.f, 0.f, 0.f, 0.f};
#pragma unroll 2
    for (int kt = 0; kt < 32; ++kt) {
        const int cur = kt & 1;
        bf16x8 nn0, nn1;
        if (kt + 2 < 32) {
            const unsigned short* src = Kb + (size_t)(kt + 2) * 4096;
            nn0 = *(const bf16x8*)(src + (size_t)row0 * 64 + cc0 * 8);
            nn1 = *(const bf16x8*)(src + (size_t)row1 * 64 + cc0 * 8);
        }
#pragma unroll
        for (int kf = 0; kf < 4; ++kf) {
            const int row = kf * 16 + r16;
            f32x4 t = {};
            t = MFMA_BF16(k_buf[cur][row * 8 + ((0 + g) ^ (row & 7))], qf0, t, 0, 0, 0);
            t = MFMA_BF16(k_buf[cur][row * 8 + ((4 + g) ^ (row & 7))], qf1, t, 0, 0, 0);
#pragma unroll
            for (int r = 0; r < 4; ++r) l4[r] += exp2_fast(t[r]);
        }
        if (kt + 1 < 32) {
            k_buf[cur ^ 1][kslot0] = pf0;
            k_buf[cur ^ 1][kslot1] = pf1;
        }
        __syncthreads();
        pf0 = nn0;
        pf1 = nn1;
    }
    float l_acc = (l4[0] + l4[1]) + (l4[2] + l4[3]);
    l_acc += __shfl_xor(l_acc, 16, 64);
    l_acc += __shfl_xor(l_acc, 32, 64);
    if (lane < 16)
        lbuf[(size_t)bh * 2048 + qt * 64 + w * 16 + lane] = l_acc;
}

// ---------------- fused attention pass 2 ----------------
// 1-D grid of 2048; same XCD map. Wave w owns q rows w*16..w*16+15.
__global__ __launch_bounds__(256) void attn_kernel(
    const unsigned short* __restrict__ Q,    // [bh][2048][64] bf16 (pre-scaled)
    const unsigned short* __restrict__ K,    // [bh][2048][64] bf16
    const unsigned short* __restrict__ VT,   // [bh][64][2048] bf16
    const float* __restrict__ lbuf,          // [bh][2048] f32 (from pass1)
    float* __restrict__ attn,                // [bh][2048][2048] fp32
    unsigned short* __restrict__ ctx)        // [b][s][h*64+d] bf16
{
    __shared__ bf16x8 k_buf[2][64 * 8];            // 16 KB dbuf
    __shared__ bf16x8 v_buf[2][64 * 8];            // 16 KB dbuf
    __shared__ unsigned long long p_buf[64 * 16];  // 8 KB, u64-typed both sides

    const int tid = threadIdx.x;
    const int lane = tid & 63;
    const int w = tid >> 6;
    const int L = blockIdx.x;
    const int xcd = L & 7, j = L >> 3;
    const int qt = j & 31;
    const int bh = ((j >> 5) << 3) | xcd;
    const int r16 = lane & 15, g = lane >> 4;

    const unsigned short* Kb = K + (size_t)bh * 2048 * 64;
    const unsigned short* Vb = VT + (size_t)bh * 64 * 2048;

    const int row0 = tid >> 3, cc0 = tid & 7;
    const int row1 = row0 + 32;
    const int kslot0 = row0 * 8 + (cc0 ^ (row0 & 7));
    const int kslot1 = row1 * 8 + (cc0 ^ (row1 & 7));

    const int qrow = w * 16 + r16;
    const unsigned short* qptr = Q + ((size_t)bh * 2048 + (size_t)qt * 64 + qrow) * 64 + g * 8;
    const bf16x8 qf0 = *(const bf16x8*)(qptr);
    const bf16x8 qf1 = *(const bf16x8*)(qptr + 32);

    const float lg2invl = -log2_fast(lbuf[(size_t)bh * 2048 + qt * 64 + qrow]);

    {
        bf16x8 a0 = *(const bf16x8*)(Kb + (size_t)row0 * 64 + cc0 * 8);
        bf16x8 a1 = *(const bf16x8*)(Kb + (size_t)row1 * 64 + cc0 * 8);
        bf16x8 b0 = *(const bf16x8*)(Vb + (size_t)row0 * 2048 + cc0 * 8);
        bf16x8 b1 = *(const bf16x8*)(Vb + (size_t)row1 * 2048 + cc0 * 8);
        k_buf[0][kslot0] = a0; k_buf[0][kslot1] = a1;
        v_buf[0][kslot0] = b0; v_buf[0][kslot1] = b1;
    }
    __syncthreads();

    float* attn_tile = attn + ((size_t)bh * 2048 + (size_t)qt * 64) * 2048;
    const f32x4 cinit = {lg2invl, lg2invl, lg2invl, lg2invl};

    f32x4 oacc[4] = {};
    for (int kt = 0; kt < 32; ++kt) {
        const int cur = kt & 1;
        bf16x8 nk0, nk1, nv0, nv1;
        if (kt != 31) {
            const unsigned short* ksrc = Kb + (size_t)(kt + 1) * 64 * 64;
            const unsigned short* vsrc = Vb + (size_t)(kt + 1) * 64;
            nk0 = *(const bf16x8*)(ksrc + (size_t)row0 * 64 + cc0 * 8);
            nk1 = *(const bf16x8*)(ksrc + (size_t)row1 * 64 + cc0 * 8);
            nv0 = *(const bf16x8*)(vsrc + (size_t)row0 * 2048 + cc0 * 8);
            nv1 = *(const bf16x8*)(vsrc + (size_t)row1 * 2048 + cc0 * 8);
        }
#pragma unroll
        for (int kf = 0; kf < 4; ++kf) {
            const int row = kf * 16 + r16;
            f32x4 t = cinit;
            t = MFMA_BF16(k_buf[cur][row * 8 + ((0 + g) ^ (row & 7))], qf0, t, 0, 0, 0);
            t = MFMA_BF16(k_buf[cur][row * 8 + ((4 + g) ^ (row & 7))], qf1, t, 0, 0, 0);
            u16x4 pk;
#pragma unroll
            for (int r = 0; r < 4; ++r) pk[r] = f2bf(exp2_fast(t[r]));
            const int c = 2 * kf + (g >> 1);
            p_buf[qrow * 16 + ((c ^ (qrow & 7)) << 1) + (g & 1)] =
                __builtin_bit_cast(unsigned long long, pk);
        }
        // full-line attn stores: 8 rows x 128B whole lines per instruction (R14)
#pragma unroll
        for (int i = 0; i < 2; ++i)
#pragma unroll
            for (int jj = 0; jj < 2; ++jj) {
                const int srow = w * 16 + i * 8 + (lane >> 3);
                const int col0 = jj * 32 + (lane & 7) * 4;
                const int c = col0 >> 3, half = (col0 >> 2) & 1;
                unsigned long long praw =
                    p_buf[srow * 16 + ((c ^ (srow & 7)) << 1) + half];
                u16x4 pk = __builtin_bit_cast(u16x4, praw);
                f32x4 pv = {bf2f(pk[0]), bf2f(pk[1]), bf2f(pk[2]), bf2f(pk[3])};
                __builtin_nontemporal_store(
                    pv, (f32x4*)(attn_tile + (size_t)srow * 2048 + kt * 64 + col0));
            }
#pragma unroll
        for (int ks = 0; ks < 2; ++ks) {
            const int cs = (ks * 4 + g) ^ (qrow & 7);
            u64x2 praw2 = {p_buf[qrow * 16 + cs * 2], p_buf[qrow * 16 + cs * 2 + 1]};
            bf16x8 a = __builtin_bit_cast(bf16x8, praw2);
#pragma unroll
            for (int df = 0; df < 4; ++df) {
                const int rowv = df * 16 + r16;
                oacc[df] = MFMA_BF16(a, v_buf[cur][rowv * 8 + ((ks * 4 + g) ^ (rowv & 7))],
                                     oacc[df], 0, 0, 0);
            }
        }
        if (kt != 31) {
            k_buf[cur ^ 1][kslot0] = nk0; k_buf[cur ^ 1][kslot1] = nk1;
            v_buf[cur ^ 1][kslot0] = nv0; v_buf[cur ^ 1][kslot1] = nv1;
        }
        __syncthreads();
    }

    // ctx write: [b][s][h*64+d] bf16
    const int b = bh >> 4, h = bh & 15;
#pragma unroll
    for (int df = 0; df < 4; ++df) {
        int d = df * 16 + r16;
#pragma unroll
        for (int r = 0; r < 4; ++r) {
            int s2 = qt * 64 + w * 16 + g * 4 + r;
            ctx[((size_t)b * 2048 + s2) * 1024 + h * 64 + d] = f2bf(oacc[df][r]);
        }
    }
}

// ---------------- launch ----------------
extern "C" void kernel_launch(void* const* d_in, const int* in_sizes, int n_in,
                              void* d_out, int out_size, void* d_ws, size_t ws_size,
                              hipStream_t stream)
{
    (void)in_sizes; (void)n_in; (void)out_size; (void)ws_size;
    const float* query = (const float*)d_in[0];
    const float* key_  = (const float*)d_in[1];
    const float* value = (const float*)d_in[2];
    const float* Wq = (const float*)d_in[3];
    const float* bq = (const float*)d_in[4];
    const float* Wk = (const float*)d_in[5];
    const float* bk = (const float*)d_in[6];
    const float* Wv = (const float*)d_in[7];
    const float* bv = (const float*)d_in[8];
    const float* Wo = (const float*)d_in[9];
    const float* bo = (const float*)d_in[10];

    char* ws = (char*)d_ws;
    unsigned short* Wt  = (unsigned short*)(ws);
    unsigned short* qb  = (unsigned short*)(ws + ((size_t)8  << 20));
    unsigned short* kb  = (unsigned short*)(ws + ((size_t)24 << 20));
    unsigned short* vtb = (unsigned short*)(ws + ((size_t)40 << 20));
    unsigned short* ctx = (unsigned short*)(ws + ((size_t)56 << 20));
    // lbuf (512KB) aliases transposed-Wq (ws[0..]), dead after the q-proj GEMM.
    float* lbuf = (float*)ws;
    float* outp = (float*)d_out;
    float* attn = outp + (size_t)4 * 2048 * 1024;

    const size_t ATTN_ELEMS = (size_t)64 * 2048 * 2048;      // 268435456
    const size_t STASH_FLOATS = (size_t)3 * 8388608 / 2;     // 12582912
    unsigned short* qkvb = (unsigned short*)(attn + (ATTN_ELEMS - STASH_FLOATS));
    unsigned short* qbf = qkvb;
    unsigned short* kbf = qkvb + 8388608;
    unsigned short* vbf = qkvb + 16777216;

    const float qscale = 0.125f * 1.44269504089f;   // fold 1/sqrt(Dh), log2e into Q

    cvt_kernel<<<dim3(4096, 3), 256, 0, stream>>>(query, key_, value, qkvb);
    wtrans_kernel<<<dim3(16, 16, 4), 256, 0, stream>>>(Wq, Wk, Wv, Wo, Wt);
    gemm_kernel<0><<<dim3(64, 8), 256, 0, stream>>>(qbf, Wt,              bq, qb,  qscale);
    gemm_kernel<0><<<dim3(64, 8), 256, 0, stream>>>(kbf, Wt + (1u << 20), bk, kb,  1.0f);
    gemm_kernel<1><<<dim3(64, 8), 256, 0, stream>>>(vbf, Wt + (2u << 20), bv, vtb, 1.0f);
    pass1_kernel<<<dim3(2048), 256, 0, stream>>>(qb, kb, lbuf);
    attn_kernel<<<dim3(2048), 256, 0, stream>>>(qb, kb, vtb, lbuf, attn, ctx);
    gemm_kernel<2><<<dim3(64, 8), 256, 0, stream>>>(ctx, Wt + (3u << 20), bo, outp, 1.0f);
}

// Round 16
// 386.066 us; speedup vs baseline: 1.0869x; 1.0869x over previous
//
#include <hip/hip_runtime.h>
#include <stdint.h>

// MHA forward, MI355X.
//   0) cvt: q/k/v fp32 -> bf16   1) wtrans: W -> Wt bf16
//   2) proj GEMMs (bf16, global_load_lds staging)
//   3) attn FUSED (R15 split regressed +51us: cross-block phase overlap between
//      latency-bound pass1 and write-bound pass2 is worth more than occupancy).
//      R16 change vs R14: pass 1 runs KVBLK=128 tiles by borrowing v_buf (dead
//      until pass-2 prologue) as rows 64..127 -> 16 iterations/barriers instead
//      of 32, depth-2 prefetch retained. Pass 2 byte-identical to R14:
//      p=2^(t-log2 l) via MFMA C-init, full-line LDS-remapped NT stores, PV MFMA.
//   4) out-proj GEMM -> fp32
//
// MFMA 16x16x32 bf16, k-chunk c = ks*4+g. C/D: col=lane&15, row=(lane>>4)*4+reg.

using bf16x8 = __attribute__((ext_vector_type(8))) short;
using f32x4  = __attribute__((ext_vector_type(4))) float;
using u16x4  = __attribute__((ext_vector_type(4))) unsigned short;
using u64x2  = __attribute__((ext_vector_type(2))) unsigned long long;

#define MFMA_BF16 __builtin_amdgcn_mfma_f32_16x16x32_bf16

__device__ __forceinline__ unsigned short f2bf(float x) {
    unsigned int u = __builtin_bit_cast(unsigned int, x);
    u = (u + 0x7FFFu + ((u >> 16) & 1u)) >> 16;   // RNE
    return (unsigned short)u;
}
__device__ __forceinline__ float bf2f(unsigned short u) {
    return __builtin_bit_cast(float, (unsigned int)u << 16);
}
__device__ __forceinline__ float exp2_fast(float x) {
    float r; asm("v_exp_f32 %0, %1" : "=v"(r) : "v"(x)); return r;
}
__device__ __forceinline__ float log2_fast(float x) {
    float r; asm("v_log_f32 %0, %1" : "=v"(r) : "v"(x)); return r;
}
__device__ __forceinline__ void gload_lds16(const unsigned short* g, bf16x8* l) {
    __builtin_amdgcn_global_load_lds(
        (const __attribute__((address_space(1))) unsigned int*)(g),
        (__attribute__((address_space(3))) unsigned int*)(l), 16, 0, 0);
}

// ---------------- fp32 -> bf16 convert (q,k,v) ----------------
__global__ __launch_bounds__(256) void cvt_kernel(
    const float* __restrict__ q, const float* __restrict__ k,
    const float* __restrict__ v, unsigned short* __restrict__ dst)
{
    const float* src = (blockIdx.y == 0) ? q : (blockIdx.y == 1) ? k : v;
    unsigned short* d = dst + (size_t)blockIdx.y * 8388608;
    size_t i = ((size_t)blockIdx.x * 256 + threadIdx.x) * 8;
    float4 a = *(const float4*)(src + i);
    float4 b = *(const float4*)(src + i + 4);
    u16x4 lo = {f2bf(a.x), f2bf(a.y), f2bf(a.z), f2bf(a.w)};
    u16x4 hi = {f2bf(b.x), f2bf(b.y), f2bf(b.z), f2bf(b.w)};
    *(u16x4*)(d + i) = lo;
    *(u16x4*)(d + i + 4) = hi;
}

// ---------------- weight transpose + bf16 convert ----------------
__global__ __launch_bounds__(256) void wtrans_kernel(
    const float* __restrict__ w0, const float* __restrict__ w1,
    const float* __restrict__ w2, const float* __restrict__ w3,
    unsigned short* __restrict__ Wt)
{
    __shared__ float tile[64][65];
    const float* src = (blockIdx.z == 0) ? w0 : (blockIdx.z == 1) ? w1 :
                       (blockIdx.z == 2) ? w2 : w3;
    unsigned short* dst = Wt + (size_t)blockIdx.z * (1u << 20);
    const int k0 = blockIdx.x * 64, n0 = blockIdx.y * 64;
    const int tid = threadIdx.x;
#pragma unroll
    for (int i = 0; i < 16; ++i) {
        int idx = i * 256 + tid;
        int kk = idx >> 6, nn = idx & 63;
        tile[kk][nn] = src[(size_t)(k0 + kk) * 1024 + n0 + nn];
    }
    __syncthreads();
#pragma unroll
    for (int i = 0; i < 16; ++i) {
        int idx = i * 256 + tid;
        int nn = idx >> 6, kk = idx & 63;
        dst[(size_t)(n0 + nn) * 1024 + k0 + kk] = f2bf(tile[kk][nn]);
    }
}

// ---------------- GEMM: C[8192,1024] = A[8192,1024](bf16) @ Bt^T + bias ----------
// OUT_MODE 0: bf16 [b][h][s][d]; 1: bf16 [b][h][d][s]; 2: fp32 row-major
template<int OUT_MODE>
__global__ __launch_bounds__(256) void gemm_kernel(
    const unsigned short* __restrict__ A, const unsigned short* __restrict__ Bt,
    const float* __restrict__ bias, void* __restrict__ Cp, float prescale)
{
    __shared__ bf16x8 Alds[1024];    // 128 rows x 8 chunks, slot-linear
    __shared__ bf16x8 Blds[1024];
    const int tid = threadIdx.x;
    const int lane = tid & 63;
    const int w = tid >> 6;
    const int wm = w >> 1, wn = w & 1;
    const int m0 = blockIdx.x * 128, n0 = blockIdx.y * 128;
    const int r16 = lane & 15, g = lane >> 4;

    f32x4 acc[4][4] = {};

    for (int kt = 0; kt < 16; ++kt) {
        const int k0 = kt * 64;
#pragma unroll
        for (int issue = 0; issue < 4; ++issue) {
            int s = issue * 256 + tid;
            int row = s >> 3, cc = (s & 7) ^ (row & 7);   // pre-swizzled source chunk
            gload_lds16(A  + (size_t)(m0 + row) * 1024 + k0 + cc * 8,
                        &Alds[issue * 256 + w * 64]);
            gload_lds16(Bt + (size_t)(n0 + row) * 1024 + k0 + cc * 8,
                        &Blds[issue * 256 + w * 64]);
        }
        __syncthreads();
#pragma unroll
        for (int ks = 0; ks < 2; ++ks) {
            bf16x8 af[4], bfr[4];
#pragma unroll
            for (int mf = 0; mf < 4; ++mf) {
                int row = wm * 64 + mf * 16 + r16;
                af[mf] = Alds[row * 8 + ((ks * 4 + g) ^ (row & 7))];
            }
#pragma unroll
            for (int nf = 0; nf < 4; ++nf) {
                int row = wn * 64 + nf * 16 + r16;
                bfr[nf] = Blds[row * 8 + ((ks * 4 + g) ^ (row & 7))];
            }
#pragma unroll
            for (int mf = 0; mf < 4; ++mf)
#pragma unroll
                for (int nf = 0; nf < 4; ++nf)
                    acc[mf][nf] = MFMA_BF16(af[mf], bfr[nf], acc[mf][nf], 0, 0, 0);
        }
        __syncthreads();
    }

#pragma unroll
    for (int nf = 0; nf < 4; ++nf) {
        const int n = n0 + wn * 64 + nf * 16 + r16;
        const float bv = bias[n];
#pragma unroll
        for (int mf = 0; mf < 4; ++mf) {
            const int mb = m0 + wm * 64 + mf * 16 + g * 4;
            if constexpr (OUT_MODE == 2) {
                float* C = (float*)Cp;
#pragma unroll
                for (int r = 0; r < 4; ++r)
                    C[(size_t)(mb + r) * 1024 + n] = acc[mf][nf][r] + bv;
            } else if constexpr (OUT_MODE == 0) {
                unsigned short* C = (unsigned short*)Cp;
                const int h = n >> 6, d = n & 63;
#pragma unroll
                for (int r = 0; r < 4; ++r) {
                    int m = mb + r;
                    int b = m >> 11, s2 = m & 2047;
                    C[((((size_t)b * 16 + h) * 2048 + s2) << 6) + d] =
                        f2bf((acc[mf][nf][r] + bv) * prescale);
                }
            } else {
                unsigned short* C = (unsigned short*)Cp;
                const int h = n >> 6, d = n & 63;
                const int b = mb >> 11, s2 = mb & 2047;
                u16x4 pk;
#pragma unroll
                for (int r = 0; r < 4; ++r) pk[r] = f2bf(acc[mf][nf][r] + bv);
                *(u16x4*)(C + (((size_t)b * 16 + h) * 64 + d) * 2048 + s2) = pk;
            }
        }
    }
}

// ---------------- fused attention ----------------
// 1-D grid of 2048; bijective XCD-grouped map: all 32 q-tiles of a bh land on one XCD.
// 4 waves; wave w owns q rows w*16..w*16+15. Swapped QK^T: lane holds
// t[k=16kf+4g+r][q=r16] (q prescaled by 0.125*log2e at projection).
__global__ __launch_bounds__(256) void attn_kernel(
    const unsigned short* __restrict__ Q,    // [bh][2048][64] bf16 (pre-scaled)
    const unsigned short* __restrict__ K,    // [bh][2048][64] bf16
    const unsigned short* __restrict__ VT,   // [bh][64][2048] bf16
    float* __restrict__ attn,                // [bh][2048][2048] fp32
    unsigned short* __restrict__ ctx)        // [b][s][h*64+d] bf16
{
    __shared__ bf16x8 k_buf[2][64 * 8];            // 16 KB dbuf
    __shared__ bf16x8 v_buf[2][64 * 8];            // 16 KB dbuf; pass-1: K rows 64..127
    __shared__ unsigned long long p_buf[64 * 16];  // 8 KB, u64-typed both sides

    const int tid = threadIdx.x;
    const int lane = tid & 63;
    const int w = tid >> 6;
    const int L = blockIdx.x;
    const int xcd = L & 7, j = L >> 3;
    const int qt = j & 31;
    const int bh = ((j >> 5) << 3) | xcd;
    const int r16 = lane & 15, g = lane >> 4;

    const unsigned short* Kb = K + (size_t)bh * 2048 * 64;
    const unsigned short* Vb = VT + (size_t)bh * 64 * 2048;

    const int row0 = tid >> 3, cc0 = tid & 7;
    const int row1 = row0 + 32;
    const int kslot0 = row0 * 8 + (cc0 ^ (row0 & 7));
    const int kslot1 = row1 * 8 + (cc0 ^ (row1 & 7));

    const int qrow = w * 16 + r16;
    const unsigned short* qptr = Q + ((size_t)bh * 2048 + (size_t)qt * 64 + qrow) * 64 + g * 8;
    const bf16x8 qf0 = *(const bf16x8*)(qptr);
    const bf16x8 qf1 = *(const bf16x8*)(qptr + 32);

    // ---- pass 1: l = sum_k 2^t  (KVBLK=128 via v_buf as rows 64..127;
    //      16 iterations/barriers; depth-2 prefetch) ----
    {
        const unsigned short* t0 = Kb;
        k_buf[0][kslot0] = *(const bf16x8*)(t0 + (size_t)row0 * 64 + cc0 * 8);
        k_buf[0][kslot1] = *(const bf16x8*)(t0 + (size_t)row1 * 64 + cc0 * 8);
        v_buf[0][kslot0] = *(const bf16x8*)(t0 + (size_t)(row0 + 64) * 64 + cc0 * 8);
        v_buf[0][kslot1] = *(const bf16x8*)(t0 + (size_t)(row1 + 64) * 64 + cc0 * 8);
    }
    bf16x8 pf0, pf1, pf2, pf3;
    {
        const unsigned short* t1 = Kb + 8192;   // tile 1 (128 rows x 64)
        pf0 = *(const bf16x8*)(t1 + (size_t)row0 * 64 + cc0 * 8);
        pf1 = *(const bf16x8*)(t1 + (size_t)row1 * 64 + cc0 * 8);
        pf2 = *(const bf16x8*)(t1 + (size_t)(row0 + 64) * 64 + cc0 * 8);
        pf3 = *(const bf16x8*)(t1 + (size_t)(row1 + 64) * 64 + cc0 * 8);
    }
    __syncthreads();

    float l4[4] = {0.f, 0.f, 0.f, 0.f};
#pragma unroll 2
    for (int kt = 0; kt < 16; ++kt) {
        const int cur = kt & 1;
        bf16x8 nn0, nn1, nn2, nn3;
        if (kt + 2 < 16) {
            const unsigned short* src = Kb + (size_t)(kt + 2) * 8192;
            nn0 = *(const bf16x8*)(src + (size_t)row0 * 64 + cc0 * 8);
            nn1 = *(const bf16x8*)(src + (size_t)row1 * 64 + cc0 * 8);
            nn2 = *(const bf16x8*)(src + (size_t)(row0 + 64) * 64 + cc0 * 8);
            nn3 = *(const bf16x8*)(src + (size_t)(row1 + 64) * 64 + cc0 * 8);
        }
#pragma unroll
        for (int kf = 0; kf < 8; ++kf) {
            const int row = kf * 16 + r16;          // 0..127
            const int rl = row & 63;
            const bf16x8* buf = (kf < 4) ? k_buf[cur] : v_buf[cur];
            f32x4 t = {};
            t = MFMA_BF16(buf[rl * 8 + ((0 + g) ^ (rl & 7))], qf0, t, 0, 0, 0);
            t = MFMA_BF16(buf[rl * 8 + ((4 + g) ^ (rl & 7))], qf1, t, 0, 0, 0);
#pragma unroll
            for (int r = 0; r < 4; ++r) l4[r] += exp2_fast(t[r]);
        }
        if (kt + 1 < 16) {
            k_buf[cur ^ 1][kslot0] = pf0;
            k_buf[cur ^ 1][kslot1] = pf1;
            v_buf[cur ^ 1][kslot0] = pf2;
            v_buf[cur ^ 1][kslot1] = pf3;
        }
        __syncthreads();
        pf0 = nn0; pf1 = nn1; pf2 = nn2; pf3 = nn3;
    }
    float l_acc = (l4[0] + l4[1]) + (l4[2] + l4[3]);
    l_acc += __shfl_xor(l_acc, 16, 64);
    l_acc += __shfl_xor(l_acc, 32, 64);
    const float lg2invl = -log2_fast(l_acc);

    // ---- pass 2: p = 2^(t + lg2invl) via MFMA C-init; full-line LDS-remapped
    //      NT stores; PV via MFMA (byte-identical to R14) ----
    {
        bf16x8 a0 = *(const bf16x8*)(Kb + (size_t)row0 * 64 + cc0 * 8);
        bf16x8 a1 = *(const bf16x8*)(Kb + (size_t)row1 * 64 + cc0 * 8);
        bf16x8 b0 = *(const bf16x8*)(Vb + (size_t)row0 * 2048 + cc0 * 8);
        bf16x8 b1 = *(const bf16x8*)(Vb + (size_t)row1 * 2048 + cc0 * 8);
        k_buf[0][kslot0] = a0; k_buf[0][kslot1] = a1;
        v_buf[0][kslot0] = b0; v_buf[0][kslot1] = b1;
    }
    __syncthreads();

    float* attn_tile = attn + ((size_t)bh * 2048 + (size_t)qt * 64) * 2048;
    const f32x4 cinit = {lg2invl, lg2invl, lg2invl, lg2invl};

    f32x4 oacc[4] = {};
    for (int kt = 0; kt < 32; ++kt) {
        const int cur = kt & 1;
        bf16x8 nk0, nk1, nv0, nv1;
        if (kt != 31) {
            const unsigned short* ksrc = Kb + (size_t)(kt + 1) * 64 * 64;
            const unsigned short* vsrc = Vb + (size_t)(kt + 1) * 64;
            nk0 = *(const bf16x8*)(ksrc + (size_t)row0 * 64 + cc0 * 8);
            nk1 = *(const bf16x8*)(ksrc + (size_t)row1 * 64 + cc0 * 8);
            nv0 = *(const bf16x8*)(vsrc + (size_t)row0 * 2048 + cc0 * 8);
            nv1 = *(const bf16x8*)(vsrc + (size_t)row1 * 2048 + cc0 * 8);
        }
#pragma unroll
        for (int kf = 0; kf < 4; ++kf) {
            const int row = kf * 16 + r16;
            f32x4 t = cinit;
            t = MFMA_BF16(k_buf[cur][row * 8 + ((0 + g) ^ (row & 7))], qf0, t, 0, 0, 0);
            t = MFMA_BF16(k_buf[cur][row * 8 + ((4 + g) ^ (row & 7))], qf1, t, 0, 0, 0);
            u16x4 pk;
#pragma unroll
            for (int r = 0; r < 4; ++r) pk[r] = f2bf(exp2_fast(t[r]));
            const int c = 2 * kf + (g >> 1);
            p_buf[qrow * 16 + ((c ^ (qrow & 7)) << 1) + (g & 1)] =
                __builtin_bit_cast(unsigned long long, pk);
        }
        // full-line attn stores: 8 rows x 128B whole lines per instruction (R14)
#pragma unroll
        for (int i = 0; i < 2; ++i)
#pragma unroll
            for (int jj = 0; jj < 2; ++jj) {
                const int srow = w * 16 + i * 8 + (lane >> 3);
                const int col0 = jj * 32 + (lane & 7) * 4;
                const int c = col0 >> 3, half = (col0 >> 2) & 1;
                unsigned long long praw =
                    p_buf[srow * 16 + ((c ^ (srow & 7)) << 1) + half];
                u16x4 pk = __builtin_bit_cast(u16x4, praw);
                f32x4 pv = {bf2f(pk[0]), bf2f(pk[1]), bf2f(pk[2]), bf2f(pk[3])};
                __builtin_nontemporal_store(
                    pv, (f32x4*)(attn_tile + (size_t)srow * 2048 + kt * 64 + col0));
            }
#pragma unroll
        for (int ks = 0; ks < 2; ++ks) {
            const int cs = (ks * 4 + g) ^ (qrow & 7);
            u64x2 praw2 = {p_buf[qrow * 16 + cs * 2], p_buf[qrow * 16 + cs * 2 + 1]};
            bf16x8 a = __builtin_bit_cast(bf16x8, praw2);
#pragma unroll
            for (int df = 0; df < 4; ++df) {
                const int rowv = df * 16 + r16;
                oacc[df] = MFMA_BF16(a, v_buf[cur][rowv * 8 + ((ks * 4 + g) ^ (rowv & 7))],
                                     oacc[df], 0, 0, 0);
            }
        }
        if (kt != 31) {
            k_buf[cur ^ 1][kslot0] = nk0; k_buf[cur ^ 1][kslot1] = nk1;
            v_buf[cur ^ 1][kslot0] = nv0; v_buf[cur ^ 1][kslot1] = nv1;
        }
        __syncthreads();
    }

    // ctx write: [b][s][h*64+d] bf16
    const int b = bh >> 4, h = bh & 15;
#pragma unroll
    for (int df = 0; df < 4; ++df) {
        int d = df * 16 + r16;
#pragma unroll
        for (int r = 0; r < 4; ++r) {
            int s2 = qt * 64 + w * 16 + g * 4 + r;
            ctx[((size_t)b * 2048 + s2) * 1024 + h * 64 + d] = f2bf(oacc[df][r]);
        }
    }
}

// ---------------- launch ----------------
extern "C" void kernel_launch(void* const* d_in, const int* in_sizes, int n_in,
                              void* d_out, int out_size, void* d_ws, size_t ws_size,
                              hipStream_t stream)
{
    (void)in_sizes; (void)n_in; (void)out_size; (void)ws_size;
    const float* query = (const float*)d_in[0];
    const float* key_  = (const float*)d_in[1];
    const float* value = (const float*)d_in[2];
    const float* Wq = (const float*)d_in[3];
    const float* bq = (const float*)d_in[4];
    const float* Wk = (const float*)d_in[5];
    const float* bk = (const float*)d_in[6];
    const float* Wv = (const float*)d_in[7];
    const float* bv = (const float*)d_in[8];
    const float* Wo = (const float*)d_in[9];
    const float* bo = (const float*)d_in[10];

    char* ws = (char*)d_ws;
    unsigned short* Wt  = (unsigned short*)(ws);
    unsigned short* qb  = (unsigned short*)(ws + ((size_t)8  << 20));
    unsigned short* kb  = (unsigned short*)(ws + ((size_t)24 << 20));
    unsigned short* vtb = (unsigned short*)(ws + ((size_t)40 << 20));
    unsigned short* ctx = (unsigned short*)(ws + ((size_t)56 << 20));
    float* outp = (float*)d_out;
    float* attn = outp + (size_t)4 * 2048 * 1024;

    const size_t ATTN_ELEMS = (size_t)64 * 2048 * 2048;      // 268435456
    const size_t STASH_FLOATS = (size_t)3 * 8388608 / 2;     // 12582912
    unsigned short* qkvb = (unsigned short*)(attn + (ATTN_ELEMS - STASH_FLOATS));
    unsigned short* qbf = qkvb;
    unsigned short* kbf = qkvb + 8388608;
    unsigned short* vbf = qkvb + 16777216;

    const float qscale = 0.125f * 1.44269504089f;   // fold 1/sqrt(Dh), log2e into Q

    cvt_kernel<<<dim3(4096, 3), 256, 0, stream>>>(query, key_, value, qkvb);
    wtrans_kernel<<<dim3(16, 16, 4), 256, 0, stream>>>(Wq, Wk, Wv, Wo, Wt);
    gemm_kernel<0><<<dim3(64, 8), 256, 0, stream>>>(qbf, Wt,              bq, qb,  qscale);
    gemm_kernel<0><<<dim3(64, 8), 256, 0, stream>>>(kbf, Wt + (1u << 20), bk, kb,  1.0f);
    gemm_kernel<1><<<dim3(64, 8), 256, 0, stream>>>(vbf, Wt + (2u << 20), bv, vtb, 1.0f);
    attn_kernel<<<dim3(2048), 256, 0, stream>>>(qb, kb, vtb, attn, ctx);
    gemm_kernel<2><<<dim3(64, 8), 256, 0, stream>>>(ctx, Wt + (3u << 20), bo, outp, 1.0f);
}

// Round 17
// 368.170 us; speedup vs baseline: 1.1397x; 1.0486x over previous
//
#include <hip/hip_runtime.h>
#include <stdint.h>

// MHA forward, MI355X.
//   1) wtrans: W[k][n] fp32 -> Wt[n][k] bf16 (x4)
//   2) proj GEMMs: A = fp32 input staged via registers + f2bf (R3 path — R17
//      drops the separate cvt kernel: R3 vs R5 A/B showed cvt+gload == fp32-A
//      within 5us, so cvt's 48MB round trip was pure overhead); B via
//      global_load_lds (pre-swizzled source). Out-proj GEMM keeps full gload
//      path (ctx is already bf16).
//   3) attn (R14, byte-identical — best measured config, 369us total):
//      fused, XCD-grouped, reg-staged dbuf K/V, pass1 depth-2 prefetch,
//      pass2 p=2^(t-log2 l) via MFMA C-init, full-line LDS-remapped NT stores,
//      PV via MFMA.
//   4) out-proj GEMM -> fp32
//
// MFMA 16x16x32 bf16, k-chunk c = ks*4+g. C/D: col=lane&15, row=(lane>>4)*4+reg.

using bf16x8 = __attribute__((ext_vector_type(8))) short;
using f32x4  = __attribute__((ext_vector_type(4))) float;
using u16x4  = __attribute__((ext_vector_type(4))) unsigned short;
using u64x2  = __attribute__((ext_vector_type(2))) unsigned long long;

#define MFMA_BF16 __builtin_amdgcn_mfma_f32_16x16x32_bf16

__device__ __forceinline__ unsigned short f2bf(float x) {
    unsigned int u = __builtin_bit_cast(unsigned int, x);
    u = (u + 0x7FFFu + ((u >> 16) & 1u)) >> 16;   // RNE
    return (unsigned short)u;
}
__device__ __forceinline__ float bf2f(unsigned short u) {
    return __builtin_bit_cast(float, (unsigned int)u << 16);
}
__device__ __forceinline__ float exp2_fast(float x) {
    float r; asm("v_exp_f32 %0, %1" : "=v"(r) : "v"(x)); return r;
}
__device__ __forceinline__ float log2_fast(float x) {
    float r; asm("v_log_f32 %0, %1" : "=v"(r) : "v"(x)); return r;
}
__device__ __forceinline__ void gload_lds16(const unsigned short* g, bf16x8* l) {
    __builtin_amdgcn_global_load_lds(
        (const __attribute__((address_space(1))) unsigned int*)(g),
        (__attribute__((address_space(3))) unsigned int*)(l), 16, 0, 0);
}

// ---------------- weight transpose + bf16 convert ----------------
__global__ __launch_bounds__(256) void wtrans_kernel(
    const float* __restrict__ w0, const float* __restrict__ w1,
    const float* __restrict__ w2, const float* __restrict__ w3,
    unsigned short* __restrict__ Wt)
{
    __shared__ float tile[64][65];
    const float* src = (blockIdx.z == 0) ? w0 : (blockIdx.z == 1) ? w1 :
                       (blockIdx.z == 2) ? w2 : w3;
    unsigned short* dst = Wt + (size_t)blockIdx.z * (1u << 20);
    const int k0 = blockIdx.x * 64, n0 = blockIdx.y * 64;
    const int tid = threadIdx.x;
#pragma unroll
    for (int i = 0; i < 16; ++i) {
        int idx = i * 256 + tid;
        int kk = idx >> 6, nn = idx & 63;
        tile[kk][nn] = src[(size_t)(k0 + kk) * 1024 + n0 + nn];
    }
    __syncthreads();
#pragma unroll
    for (int i = 0; i < 16; ++i) {
        int idx = i * 256 + tid;
        int nn = idx >> 6, kk = idx & 63;
        dst[(size_t)(n0 + nn) * 1024 + k0 + kk] = f2bf(tile[kk][nn]);
    }
}

// ---------------- GEMM: C[8192,1024] = A[8192,1024] @ Bt^T + bias ----------
// A_BF16: bf16 A via global_load_lds; else fp32 A via reg staging + f2bf.
// B always via global_load_lds (pre-swizzled source).
// OUT_MODE 0: bf16 [b][h][s][d]; 1: bf16 [b][h][d][s]; 2: fp32 row-major
template<bool A_BF16, int OUT_MODE>
__global__ __launch_bounds__(256) void gemm_kernel(
    const void* __restrict__ Aip, const unsigned short* __restrict__ Bt,
    const float* __restrict__ bias, void* __restrict__ Cp, float prescale)
{
    __shared__ bf16x8 Alds[1024];    // 128 rows x 8 chunks, slot-linear
    __shared__ bf16x8 Blds[1024];
    const int tid = threadIdx.x;
    const int lane = tid & 63;
    const int w = tid >> 6;
    const int wm = w >> 1, wn = w & 1;
    const int m0 = blockIdx.x * 128, n0 = blockIdx.y * 128;
    const int r16 = lane & 15, g = lane >> 4;

    f32x4 acc[4][4] = {};

    for (int kt = 0; kt < 16; ++kt) {
        const int k0 = kt * 64;
#pragma unroll
        for (int issue = 0; issue < 4; ++issue) {
            int s = issue * 256 + tid;
            int row = s >> 3, cc = (s & 7) ^ (row & 7);   // pre-swizzled source chunk
            gload_lds16(Bt + (size_t)(n0 + row) * 1024 + k0 + cc * 8,
                        &Blds[issue * 256 + w * 64]);
        }
        if constexpr (A_BF16) {
            const unsigned short* A = (const unsigned short*)Aip;
#pragma unroll
            for (int issue = 0; issue < 4; ++issue) {
                int s = issue * 256 + tid;
                int row = s >> 3, cc = (s & 7) ^ (row & 7);
                gload_lds16(A + (size_t)(m0 + row) * 1024 + k0 + cc * 8,
                            &Alds[issue * 256 + w * 64]);
            }
        } else {
            const float* A = (const float*)Aip;
#pragma unroll
            for (int i = 0; i < 4; ++i) {
                int c = i * 256 + tid;
                int row = c >> 3, cc = c & 7;
                const float* sp = A + (size_t)(m0 + row) * 1024 + k0 + cc * 8;
                float4 v0 = *(const float4*)sp;
                float4 v1 = *(const float4*)(sp + 4);
                bf16x8 v;
                v[0] = f2bf(v0.x); v[1] = f2bf(v0.y); v[2] = f2bf(v0.z); v[3] = f2bf(v0.w);
                v[4] = f2bf(v1.x); v[5] = f2bf(v1.y); v[6] = f2bf(v1.z); v[7] = f2bf(v1.w);
                Alds[row * 8 + (cc ^ (row & 7))] = v;
            }
        }
        __syncthreads();
#pragma unroll
        for (int ks = 0; ks < 2; ++ks) {
            bf16x8 af[4], bfr[4];
#pragma unroll
            for (int mf = 0; mf < 4; ++mf) {
                int row = wm * 64 + mf * 16 + r16;
                af[mf] = Alds[row * 8 + ((ks * 4 + g) ^ (row & 7))];
            }
#pragma unroll
            for (int nf = 0; nf < 4; ++nf) {
                int row = wn * 64 + nf * 16 + r16;
                bfr[nf] = Blds[row * 8 + ((ks * 4 + g) ^ (row & 7))];
            }
#pragma unroll
            for (int mf = 0; mf < 4; ++mf)
#pragma unroll
                for (int nf = 0; nf < 4; ++nf)
                    acc[mf][nf] = MFMA_BF16(af[mf], bfr[nf], acc[mf][nf], 0, 0, 0);
        }
        __syncthreads();
    }

#pragma unroll
    for (int nf = 0; nf < 4; ++nf) {
        const int n = n0 + wn * 64 + nf * 16 + r16;
        const float bv = bias[n];
#pragma unroll
        for (int mf = 0; mf < 4; ++mf) {
            const int mb = m0 + wm * 64 + mf * 16 + g * 4;
            if constexpr (OUT_MODE == 2) {
                float* C = (float*)Cp;
#pragma unroll
                for (int r = 0; r < 4; ++r)
                    C[(size_t)(mb + r) * 1024 + n] = acc[mf][nf][r] + bv;
            } else if constexpr (OUT_MODE == 0) {
                unsigned short* C = (unsigned short*)Cp;
                const int h = n >> 6, d = n & 63;
#pragma unroll
                for (int r = 0; r < 4; ++r) {
                    int m = mb + r;
                    int b = m >> 11, s2 = m & 2047;
                    C[((((size_t)b * 16 + h) * 2048 + s2) << 6) + d] =
                        f2bf((acc[mf][nf][r] + bv) * prescale);
                }
            } else {
                unsigned short* C = (unsigned short*)Cp;
                const int h = n >> 6, d = n & 63;
                const int b = mb >> 11, s2 = mb & 2047;
                u16x4 pk;
#pragma unroll
                for (int r = 0; r < 4; ++r) pk[r] = f2bf(acc[mf][nf][r] + bv);
                *(u16x4*)(C + (((size_t)b * 16 + h) * 64 + d) * 2048 + s2) = pk;
            }
        }
    }
}

// ---------------- fused attention (R14, byte-identical) ----------------
// 1-D grid of 2048; bijective XCD-grouped map: all 32 q-tiles of a bh land on one XCD.
// 4 waves; wave w owns q rows w*16..w*16+15. Swapped QK^T: lane holds
// t[k=16kf+4g+r][q=r16] (q prescaled by 0.125*log2e at projection).
__global__ __launch_bounds__(256) void attn_kernel(
    const unsigned short* __restrict__ Q,    // [bh][2048][64] bf16 (pre-scaled)
    const unsigned short* __restrict__ K,    // [bh][2048][64] bf16
    const unsigned short* __restrict__ VT,   // [bh][64][2048] bf16
    float* __restrict__ attn,                // [bh][2048][2048] fp32
    unsigned short* __restrict__ ctx)        // [b][s][h*64+d] bf16
{
    __shared__ bf16x8 k_buf[2][64 * 8];            // 16 KB dbuf
    __shared__ bf16x8 v_buf[2][64 * 8];            // 16 KB dbuf
    __shared__ unsigned long long p_buf[64 * 16];  // 8 KB, u64-typed both sides

    const int tid = threadIdx.x;
    const int lane = tid & 63;
    const int w = tid >> 6;
    const int L = blockIdx.x;
    const int xcd = L & 7, j = L >> 3;
    const int qt = j & 31;
    const int bh = ((j >> 5) << 3) | xcd;
    const int r16 = lane & 15, g = lane >> 4;

    const unsigned short* Kb = K + (size_t)bh * 2048 * 64;
    const unsigned short* Vb = VT + (size_t)bh * 64 * 2048;

    const int row0 = tid >> 3, cc0 = tid & 7;
    const int row1 = row0 + 32;
    const int kslot0 = row0 * 8 + (cc0 ^ (row0 & 7));
    const int kslot1 = row1 * 8 + (cc0 ^ (row1 & 7));

    const int qrow = w * 16 + r16;
    const unsigned short* qptr = Q + ((size_t)bh * 2048 + (size_t)qt * 64 + qrow) * 64 + g * 8;
    const bf16x8 qf0 = *(const bf16x8*)(qptr);
    const bf16x8 qf1 = *(const bf16x8*)(qptr + 32);

    // ---- pass 1: l = sum_k 2^t  (depth-2 prefetch, R13) ----
    k_buf[0][kslot0] = *(const bf16x8*)(Kb + (size_t)row0 * 64 + cc0 * 8);
    k_buf[0][kslot1] = *(const bf16x8*)(Kb + (size_t)row1 * 64 + cc0 * 8);
    bf16x8 pf0 = *(const bf16x8*)(Kb + 4096 + (size_t)row0 * 64 + cc0 * 8);
    bf16x8 pf1 = *(const bf16x8*)(Kb + 4096 + (size_t)row1 * 64 + cc0 * 8);
    __syncthreads();

    float l4[4] = {0.f, 0.f, 0.f, 0.f};
#pragma unroll 2
    for (int kt = 0; kt < 32; ++kt) {
        const int cur = kt & 1;
        bf16x8 nn0, nn1;
        if (kt + 2 < 32) {
            const unsigned short* src = Kb + (size_t)(kt + 2) * 4096;
            nn0 = *(const bf16x8*)(src + (size_t)row0 * 64 + cc0 * 8);
            nn1 = *(const bf16x8*)(src + (size_t)row1 * 64 + cc0 * 8);
        }
#pragma unroll
        for (int kf = 0; kf < 4; ++kf) {
            const int row = kf * 16 + r16;
            f32x4 t = {};
            t = MFMA_BF16(k_buf[cur][row * 8 + ((0 + g) ^ (row & 7))], qf0, t, 0, 0, 0);
            t = MFMA_BF16(k_buf[cur][row * 8 + ((4 + g) ^ (row & 7))], qf1, t, 0, 0, 0);
#pragma unroll
            for (int r = 0; r < 4; ++r) l4[r] += exp2_fast(t[r]);
        }
        if (kt + 1 < 32) {
            k_buf[cur ^ 1][kslot0] = pf0;
            k_buf[cur ^ 1][kslot1] = pf1;
        }
        __syncthreads();
        pf0 = nn0;
        pf1 = nn1;
    }
    float l_acc = (l4[0] + l4[1]) + (l4[2] + l4[3]);
    l_acc += __shfl_xor(l_acc, 16, 64);
    l_acc += __shfl_xor(l_acc, 32, 64);
    const float lg2invl = -log2_fast(l_acc);

    // ---- pass 2: p = 2^(t + lg2invl) via MFMA C-init; full-line LDS-remapped
    //      NT stores; PV via MFMA ----
    {
        bf16x8 a0 = *(const bf16x8*)(Kb + (size_t)row0 * 64 + cc0 * 8);
        bf16x8 a1 = *(const bf16x8*)(Kb + (size_t)row1 * 64 + cc0 * 8);
        bf16x8 b0 = *(const bf16x8*)(Vb + (size_t)row0 * 2048 + cc0 * 8);
        bf16x8 b1 = *(const bf16x8*)(Vb + (size_t)row1 * 2048 + cc0 * 8);
        k_buf[0][kslot0] = a0; k_buf[0][kslot1] = a1;
        v_buf[0][kslot0] = b0; v_buf[0][kslot1] = b1;
    }
    __syncthreads();

    float* attn_tile = attn + ((size_t)bh * 2048 + (size_t)qt * 64) * 2048;
    const f32x4 cinit = {lg2invl, lg2invl, lg2invl, lg2invl};

    f32x4 oacc[4] = {};
    for (int kt = 0; kt < 32; ++kt) {
        const int cur = kt & 1;
        bf16x8 nk0, nk1, nv0, nv1;
        if (kt != 31) {
            const unsigned short* ksrc = Kb + (size_t)(kt + 1) * 64 * 64;
            const unsigned short* vsrc = Vb + (size_t)(kt + 1) * 64;
            nk0 = *(const bf16x8*)(ksrc + (size_t)row0 * 64 + cc0 * 8);
            nk1 = *(const bf16x8*)(ksrc + (size_t)row1 * 64 + cc0 * 8);
            nv0 = *(const bf16x8*)(vsrc + (size_t)row0 * 2048 + cc0 * 8);
            nv1 = *(const bf16x8*)(vsrc + (size_t)row1 * 2048 + cc0 * 8);
        }
#pragma unroll
        for (int kf = 0; kf < 4; ++kf) {
            const int row = kf * 16 + r16;
            f32x4 t = cinit;
            t = MFMA_BF16(k_buf[cur][row * 8 + ((0 + g) ^ (row & 7))], qf0, t, 0, 0, 0);
            t = MFMA_BF16(k_buf[cur][row * 8 + ((4 + g) ^ (row & 7))], qf1, t, 0, 0, 0);
            u16x4 pk;
#pragma unroll
            for (int r = 0; r < 4; ++r) pk[r] = f2bf(exp2_fast(t[r]));
            const int c = 2 * kf + (g >> 1);
            p_buf[qrow * 16 + ((c ^ (qrow & 7)) << 1) + (g & 1)] =
                __builtin_bit_cast(unsigned long long, pk);
        }
        // full-line attn stores: 8 rows x 128B whole lines per instruction (R14)
#pragma unroll
        for (int i = 0; i < 2; ++i)
#pragma unroll
            for (int jj = 0; jj < 2; ++jj) {
                const int srow = w * 16 + i * 8 + (lane >> 3);
                const int col0 = jj * 32 + (lane & 7) * 4;
                const int c = col0 >> 3, half = (col0 >> 2) & 1;
                unsigned long long praw =
                    p_buf[srow * 16 + ((c ^ (srow & 7)) << 1) + half];
                u16x4 pk = __builtin_bit_cast(u16x4, praw);
                f32x4 pv = {bf2f(pk[0]), bf2f(pk[1]), bf2f(pk[2]), bf2f(pk[3])};
                __builtin_nontemporal_store(
                    pv, (f32x4*)(attn_tile + (size_t)srow * 2048 + kt * 64 + col0));
            }
#pragma unroll
        for (int ks = 0; ks < 2; ++ks) {
            const int cs = (ks * 4 + g) ^ (qrow & 7);
            u64x2 praw2 = {p_buf[qrow * 16 + cs * 2], p_buf[qrow * 16 + cs * 2 + 1]};
            bf16x8 a = __builtin_bit_cast(bf16x8, praw2);
#pragma unroll
            for (int df = 0; df < 4; ++df) {
                const int rowv = df * 16 + r16;
                oacc[df] = MFMA_BF16(a, v_buf[cur][rowv * 8 + ((ks * 4 + g) ^ (rowv & 7))],
                                     oacc[df], 0, 0, 0);
            }
        }
        if (kt != 31) {
            k_buf[cur ^ 1][kslot0] = nk0; k_buf[cur ^ 1][kslot1] = nk1;
            v_buf[cur ^ 1][kslot0] = nv0; v_buf[cur ^ 1][kslot1] = nv1;
        }
        __syncthreads();
    }

    // ctx write: [b][s][h*64+d] bf16
    const int b = bh >> 4, h = bh & 15;
#pragma unroll
    for (int df = 0; df < 4; ++df) {
        int d = df * 16 + r16;
#pragma unroll
        for (int r = 0; r < 4; ++r) {
            int s2 = qt * 64 + w * 16 + g * 4 + r;
            ctx[((size_t)b * 2048 + s2) * 1024 + h * 64 + d] = f2bf(oacc[df][r]);
        }
    }
}

// ---------------- launch ----------------
extern "C" void kernel_launch(void* const* d_in, const int* in_sizes, int n_in,
                              void* d_out, int out_size, void* d_ws, size_t ws_size,
                              hipStream_t stream)
{
    (void)in_sizes; (void)n_in; (void)out_size; (void)ws_size;
    const float* query = (const float*)d_in[0];
    const float* key_  = (const float*)d_in[1];
    const float* value = (const float*)d_in[2];
    const float* Wq = (const float*)d_in[3];
    const float* bq = (const float*)d_in[4];
    const float* Wk = (const float*)d_in[5];
    const float* bk = (const float*)d_in[6];
    const float* Wv = (const float*)d_in[7];
    const float* bv = (const float*)d_in[8];
    const float* Wo = (const float*)d_in[9];
    const float* bo = (const float*)d_in[10];

    char* ws = (char*)d_ws;
    unsigned short* Wt  = (unsigned short*)(ws);
    unsigned short* qb  = (unsigned short*)(ws + ((size_t)8  << 20));
    unsigned short* kb  = (unsigned short*)(ws + ((size_t)24 << 20));
    unsigned short* vtb = (unsigned short*)(ws + ((size_t)40 << 20));
    unsigned short* ctx = (unsigned short*)(ws + ((size_t)56 << 20));
    float* outp = (float*)d_out;
    float* attn = outp + (size_t)4 * 2048 * 1024;

    const float qscale = 0.125f * 1.44269504089f;   // fold 1/sqrt(Dh), log2e into Q

    wtrans_kernel<<<dim3(16, 16, 4), 256, 0, stream>>>(Wq, Wk, Wv, Wo, Wt);
    gemm_kernel<false, 0><<<dim3(64, 8), 256, 0, stream>>>(query, Wt,              bq, qb,  qscale);
    gemm_kernel<false, 0><<<dim3(64, 8), 256, 0, stream>>>(key_,  Wt + (1u << 20), bk, kb,  1.0f);
    gemm_kernel<false, 1><<<dim3(64, 8), 256, 0, stream>>>(value, Wt + (2u << 20), bv, vtb, 1.0f);
    attn_kernel<<<dim3(2048), 256, 0, stream>>>(qb, kb, vtb, attn, ctx);
    gemm_kernel<true, 2><<<dim3(64, 8), 256, 0, stream>>>(ctx, Wt + (3u << 20), bo, outp, 1.0f);
}